// Round 1
// baseline (25.143 us; speedup 1.0000x reference)
//
#include <hip/hip_runtime.h>

// out[r,s,j,a] = sum_b skts[r,j,a,b] * pts_h[r,s,b],  a in 0..2
// pts:  [R=4096, S=96, 3]   f32
// skts: [R=4096, J=24, 4,4] f32
// out:  [R, S, J, 3]        f32  (113 MB -> store-bound)

constexpr int S_DIM = 96;
constexpr int J_DIM = 24;
constexpr int SKT_STRIDE = 17;   // pad 16 -> 17 (coprime with 32 banks): conflict-free j-indexed reads
constexpr int BLOCK = 256;
constexpr int PAIRS = S_DIM * J_DIM;          // 2304 = 9 * 256 exactly
constexpr int ITERS = PAIRS / BLOCK;          // 9

__global__ __launch_bounds__(BLOCK) void w2l_kernel(
    const float* __restrict__ pts,
    const float* __restrict__ skts,
    float* __restrict__ out) {

    const int r = blockIdx.x;
    const int tid = threadIdx.x;

    __shared__ float s_skt[J_DIM * SKT_STRIDE];  // 408 f32
    __shared__ float s_pts[S_DIM * 3];           // 288 f32

    const float* __restrict__ skt_g = skts + (size_t)r * (J_DIM * 16);
    const float* __restrict__ pts_g = pts  + (size_t)r * (S_DIM * 3);

    // Stage both inputs for this ray into LDS (coalesced scalar loads; 672 f32 total).
    for (int i = tid; i < J_DIM * 16 + S_DIM * 3; i += BLOCK) {
        if (i < J_DIM * 16) {
            s_skt[(i >> 4) * SKT_STRIDE + (i & 15)] = skt_g[i];
        } else {
            int k = i - J_DIM * 16;
            s_pts[k] = pts_g[k];
        }
    }
    __syncthreads();

    float* __restrict__ out_r = out + (size_t)r * (PAIRS * 3);

    #pragma unroll
    for (int it = 0; it < ITERS; ++it) {
        const int p = tid + it * BLOCK;      // p = s*24 + j  -> consecutive lanes write consecutive 12B
        const int s = p / J_DIM;             // const divide -> magic multiply
        const int j = p - s * J_DIM;

        const float x = s_pts[s * 3 + 0];    // broadcast within 24-lane groups
        const float y = s_pts[s * 3 + 1];
        const float z = s_pts[s * 3 + 2];

        const float* __restrict__ b = &s_skt[j * SKT_STRIDE];
        const float o0 = fmaf(b[0], x, fmaf(b[1], y, fmaf(b[2],  z, b[3])));
        const float o1 = fmaf(b[4], x, fmaf(b[5], y, fmaf(b[6],  z, b[7])));
        const float o2 = fmaf(b[8], x, fmaf(b[9], y, fmaf(b[10], z, b[11])));

        *reinterpret_cast<float3*>(out_r + (size_t)p * 3) = make_float3(o0, o1, o2);
    }
}

extern "C" void kernel_launch(void* const* d_in, const int* in_sizes, int n_in,
                              void* d_out, int out_size, void* d_ws, size_t ws_size,
                              hipStream_t stream) {
    const float* pts  = (const float*)d_in[0];
    const float* skts = (const float*)d_in[1];
    float* out = (float*)d_out;

    const int R = in_sizes[0] / (S_DIM * 3);   // 4096
    w2l_kernel<<<R, BLOCK, 0, stream>>>(pts, skts, out);
}

// Round 2
// 23.915 us; speedup vs baseline: 1.0513x; 1.0513x over previous
//
#include <hip/hip_runtime.h>

// out[r,s,j,a] = sum_b skts[r,j,a,b] * pts_h[r,s,b],  a in 0..2
// pts:  [R=4096, S=96, 3]   f32
// skts: [R=4096, J=24, 4,4] f32
// out:  [R, S, J, 3]        f32  (113 MB -> store-bound)
//
// v2: 2 rays/block with register prefetch of ray i+1's inputs issued BEFORE
// ray i's store loop -> staging latency hides under the store stream.

constexpr int S_DIM = 96;
constexpr int J_DIM = 24;
constexpr int STR   = 17;                 // 16->17 pad: j*17 injective mod 32 banks
constexpr int BLOCK = 256;
constexpr int PAIRS = S_DIM * J_DIM;      // 2304 = 9 * 256
constexpr int ITERS = PAIRS / BLOCK;      // 9
constexpr int RPB   = 2;                  // rays per block
constexpr int SKT_F4 = J_DIM * 4;         // 96 float4 (384 floats)
constexpr int PTS_F4 = S_DIM * 3 / 4;     // 72 float4 (288 floats)
constexpr int TOT_F4 = SKT_F4 + PTS_F4;   // 168

__global__ __launch_bounds__(BLOCK) void w2l_kernel(
    const float* __restrict__ pts,
    const float* __restrict__ skts,
    float* __restrict__ out) {

    const int tid = threadIdx.x;
    const int r0  = blockIdx.x * RPB;

    __shared__ float s_skt[RPB][J_DIM * STR];   // 2 x 408 f32
    __shared__ float s_pts[RPB][S_DIM * 3];     // 2 x 288 f32

    auto load_ray = [&](int r, float4& v) {
        if (tid < SKT_F4) {
            v = reinterpret_cast<const float4*>(skts + (size_t)r * (J_DIM * 16))[tid];
        } else if (tid < TOT_F4) {
            v = reinterpret_cast<const float4*>(pts + (size_t)r * (S_DIM * 3))[tid - SKT_F4];
        }
    };
    auto write_lds = [&](int buf, const float4& v) {
        if (tid < SKT_F4) {
            int row = tid >> 2, c = (tid & 3) * 4;
            float* d = &s_skt[buf][row * STR + c];
            d[0] = v.x; d[1] = v.y; d[2] = v.z; d[3] = v.w;
        } else if (tid < TOT_F4) {
            float* d = &s_pts[buf][(tid - SKT_F4) * 4];
            d[0] = v.x; d[1] = v.y; d[2] = v.z; d[3] = v.w;
        }
    };

    float4 v;
    load_ray(r0, v);
    write_lds(0, v);
    __syncthreads();

    for (int rr = 0; rr < RPB; ++rr) {
        float4 nv;
        if (rr + 1 < RPB) load_ray(r0 + rr + 1, nv);   // async; waitcnt only at write_lds

        float* __restrict__ out_r = out + (size_t)(r0 + rr) * (PAIRS * 3);
        const float* __restrict__ sk = s_skt[rr];
        const float* __restrict__ sp = s_pts[rr];

        #pragma unroll
        for (int it = 0; it < ITERS; ++it) {
            const int p = tid + it * BLOCK;   // consecutive lanes -> contiguous 12B stores
            const int s = p / J_DIM;
            const int j = p - s * J_DIM;

            const float x = sp[s * 3 + 0];
            const float y = sp[s * 3 + 1];
            const float z = sp[s * 3 + 2];

            const float* __restrict__ b = &sk[j * STR];
            const float o0 = fmaf(b[0], x, fmaf(b[1], y, fmaf(b[2],  z, b[3])));
            const float o1 = fmaf(b[4], x, fmaf(b[5], y, fmaf(b[6],  z, b[7])));
            const float o2 = fmaf(b[8], x, fmaf(b[9], y, fmaf(b[10], z, b[11])));

            *reinterpret_cast<float3*>(out_r + (size_t)p * 3) = make_float3(o0, o1, o2);
        }

        if (rr + 1 < RPB) {
            write_lds(rr + 1, nv);
            __syncthreads();
        }
    }
}

extern "C" void kernel_launch(void* const* d_in, const int* in_sizes, int n_in,
                              void* d_out, int out_size, void* d_ws, size_t ws_size,
                              hipStream_t stream) {
    const float* pts  = (const float*)d_in[0];
    const float* skts = (const float*)d_in[1];
    float* out = (float*)d_out;

    const int R = in_sizes[0] / (S_DIM * 3);   // 4096
    w2l_kernel<<<R / RPB, BLOCK, 0, stream>>>(pts, skts, out);
}